// Round 15
// baseline (20242.278 us; speedup 1.0000x reference)
//
#include <hip/hip_runtime.h>
#include <math.h>

#define SS 2048
#define BB 64
#define XDIM 64
#define DXF 128
#define HH 256
#define DHH 128
#define CHUNK 16
#define NW (SS / CHUNK)   // 128 windows

typedef float v2f __attribute__((ext_vector_type(2)));

// tanh(x) = 1 - 2/(exp(2x)+1); __expf -> v_exp_f32, ~1e-6 abs err, saturates correctly.
__device__ __forceinline__ float ftanh(float x) {
    float e = __expf(2.0f * x);
    return 1.0f - 2.0f / (e + 1.0f);
}

template <int CTRL>
__device__ __forceinline__ float dpp_mov_f(float x) {
    return __int_as_float(__builtin_amdgcn_update_dpp(
        0, __float_as_int(x), CTRL, 0xF, 0xF, true));
}

// ---------------------------------------------------------------------------
// K1: u[e,i] = bih[i]+bhh[i] + sum_j tanh(bx[j] + sum_m x[e,m]Wx[m,j]) * Wih[i,j]
// 64 rows/block, 256 threads. Register tiles: 4 cols x 4 rows, float4 LDS reads.
// ---------------------------------------------------------------------------
__global__ __launch_bounds__(256) void k1_featu(
    const float* __restrict__ x, const float* __restrict__ Wx,
    const float* __restrict__ bx, const float* __restrict__ Wih,
    const float* __restrict__ bih, const float* __restrict__ bhh,
    float* __restrict__ u)
{
    __shared__ float xs[64][XDIM];   // 16KB
    __shared__ float fs[64][DXF];    // 32KB
    const int tid = threadIdx.x;
    const size_t row0 = (size_t)blockIdx.x * 64;

    for (int v = tid; v < 64 * XDIM; v += 256) {
        int r = v >> 6, m = v & 63;
        xs[r][m] = x[(row0 + r) * XDIM + m];
    }
    __syncthreads();

    // stage 2: fs = tanh(xs @ Wx + bx). cols: cq+32j; rows: 8ru..8ru+7
    {
        const int cq = tid & 31;
        const int ru = tid >> 5;
        v2f aA[2][4], aB[2][4];
        #pragma unroll
        for (int g = 0; g < 2; ++g)
            #pragma unroll
            for (int i = 0; i < 4; ++i) { aA[g][i] = (v2f)0.f; aB[g][i] = (v2f)0.f; }

        #pragma unroll
        for (int kc = 0; kc < 4; ++kc) {          // K=64, KC=16
            v2f wA[16], wB[16];
            #pragma unroll
            for (int k = 0; k < 16; ++k) {
                const float* wp = Wx + (kc * 16 + k) * DXF + cq;
                wA[k] = (v2f){wp[0],  wp[32]};
                wB[k] = (v2f){wp[64], wp[96]};
            }
            #pragma unroll
            for (int g = 0; g < 2; ++g) {
                const int rb = 8 * ru + 4 * g;
                #pragma unroll
                for (int k4 = 0; k4 < 4; ++k4) {
                    float4 xv[4];
                    #pragma unroll
                    for (int i = 0; i < 4; ++i)
                        xv[i] = *(const float4*)&xs[rb + i][kc * 16 + 4 * k4];
                    #pragma unroll
                    for (int i = 0; i < 4; ++i) {
                        #pragma unroll
                        for (int e = 0; e < 4; ++e) {
                            const float xe = (e == 0) ? xv[i].x : (e == 1) ? xv[i].y
                                           : (e == 2) ? xv[i].z : xv[i].w;
                            const v2f xb = (v2f){xe, xe};
                            aA[g][i] += wA[4 * k4 + e] * xb;
                            aB[g][i] += wB[4 * k4 + e] * xb;
                        }
                    }
                }
            }
        }
        const float b0 = bx[cq], b1 = bx[cq + 32], b2 = bx[cq + 64], b3 = bx[cq + 96];
        #pragma unroll
        for (int g = 0; g < 2; ++g)
            #pragma unroll
            for (int i = 0; i < 4; ++i) {
                const int r = 8 * ru + 4 * g + i;
                fs[r][cq]      = ftanh(aA[g][i].x + b0);
                fs[r][cq + 32] = ftanh(aA[g][i].y + b1);
                fs[r][cq + 64] = ftanh(aB[g][i].x + b2);
                fs[r][cq + 96] = ftanh(aB[g][i].y + b3);
            }
    }
    __syncthreads();

    // stage 3: u = fs @ Wih^T + bih + bhh. cols q4+64j; rows 16rq..16rq+15
    {
        const int q4 = tid & 63;
        const int rq = tid >> 6;
        v2f aA[4][4], aB[4][4];
        #pragma unroll
        for (int g = 0; g < 4; ++g)
            #pragma unroll
            for (int i = 0; i < 4; ++i) { aA[g][i] = (v2f)0.f; aB[g][i] = (v2f)0.f; }

        #pragma unroll
        for (int kc = 0; kc < 8; ++kc) {          // K=128, KC=16
            v2f wA[16], wB[16];
            #pragma unroll
            for (int k4 = 0; k4 < 4; ++k4) {
                const float4 w0 = *(const float4*)(Wih + (size_t)(q4      ) * DXF + kc * 16 + 4 * k4);
                const float4 w1 = *(const float4*)(Wih + (size_t)(q4 +  64) * DXF + kc * 16 + 4 * k4);
                const float4 w2 = *(const float4*)(Wih + (size_t)(q4 + 128) * DXF + kc * 16 + 4 * k4);
                const float4 w3 = *(const float4*)(Wih + (size_t)(q4 + 192) * DXF + kc * 16 + 4 * k4);
                wA[4 * k4 + 0] = (v2f){w0.x, w1.x}; wA[4 * k4 + 1] = (v2f){w0.y, w1.y};
                wA[4 * k4 + 2] = (v2f){w0.z, w1.z}; wA[4 * k4 + 3] = (v2f){w0.w, w1.w};
                wB[4 * k4 + 0] = (v2f){w2.x, w3.x}; wB[4 * k4 + 1] = (v2f){w2.y, w3.y};
                wB[4 * k4 + 2] = (v2f){w2.z, w3.z}; wB[4 * k4 + 3] = (v2f){w2.w, w3.w};
            }
            #pragma unroll
            for (int g = 0; g < 4; ++g) {
                const int rb = 16 * rq + 4 * g;
                #pragma unroll
                for (int k4 = 0; k4 < 4; ++k4) {
                    float4 fv[4];
                    #pragma unroll
                    for (int i = 0; i < 4; ++i)
                        fv[i] = *(const float4*)&fs[rb + i][kc * 16 + 4 * k4];
                    #pragma unroll
                    for (int i = 0; i < 4; ++i) {
                        #pragma unroll
                        for (int e = 0; e < 4; ++e) {
                            const float fe = (e == 0) ? fv[i].x : (e == 1) ? fv[i].y
                                           : (e == 2) ? fv[i].z : fv[i].w;
                            const v2f fb = (v2f){fe, fe};
                            aA[g][i] += wA[4 * k4 + e] * fb;
                            aB[g][i] += wB[4 * k4 + e] * fb;
                        }
                    }
                }
            }
        }
        const float b0 = bih[q4]       + bhh[q4];
        const float b1 = bih[q4 + 64]  + bhh[q4 + 64];
        const float b2 = bih[q4 + 128] + bhh[q4 + 128];
        const float b3 = bih[q4 + 192] + bhh[q4 + 192];
        #pragma unroll
        for (int g = 0; g < 4; ++g)
            #pragma unroll
            for (int i = 0; i < 4; ++i) {
                const size_t row = row0 + 16 * rq + 4 * g + i;
                u[row * HH + q4]       = aA[g][i].x + b0;
                u[row * HH + q4 + 64]  = aA[g][i].y + b1;
                u[row * HH + q4 + 128] = aB[g][i].x + b2;
                u[row * HH + q4 + 192] = aB[g][i].y + b3;
            }
    }
}

// ---------------------------------------------------------------------------
// K2: sequential recurrence. 2 batches/block (512 thr = 8 waves), grid = 32.
//
// R20: R15 post-mortem (measured, 19520us!). VGPR_Count=128 with 256 weight
// floats/lane needed => the RA SPILLED the weights to scratch: WRITE_SIZE
// 131MB -> 352MB (+221MB spill traffic), VALUBusy 0.98%, 11x regression.
// Root cause: amdgpu_waves_per_eu(2, 4) — the max=4 end of the range let
// the backend target 4 waves/EU = 128-VGPR budget. THE FIX: pin the range,
// waves_per_eu(2, 2) => budget 512/2 = 256 VGPRs; ~190-220 live, no spill.
// (Same lesson as the R5-era __launch_bounds__ note: never leave the
// backend a reason to shrink the register budget below the resident set.)
//
// Everything else identical to the R15 kernel (passed correctness):
//   * u staged through LDS in 16-step chunks, double-buffered: loads issued
//     at window start, ds_write at window end (~15 steps HBM slack);
//     per-step u = 1 conflict-free ds_read_b32, no global load on chain.
//   * 2 batches co-resident (2 waves/SIMD) so the other chain's waves fill
//     dependency stalls.
//   * 256 weight floats/lane (pinned), zero-conflict h-read rotation,
//     3-stage DPP reduce (xor7=0x141, xor1=0xB1, xor2=0x4E),
//     rl = 4*pb2+2*pb0+pb1, every lane owns one row, lgkm-only barrier.
// ---------------------------------------------------------------------------
__global__ __launch_bounds__(512)
__attribute__((amdgpu_waves_per_eu(2, 2)))
void k2_rnn(
    const float* __restrict__ u, const float* __restrict__ Whh,
    const float* __restrict__ sigmas, float* __restrict__ hist)
{
    __shared__ float hbuf[2][2][HH];              // [half][cur][row]   4KB
    __shared__ float ubuf[2][2][CHUNK][HH];       // [half][buf][s][row] 64KB
    const int tid  = threadIdx.x;
    const int half = tid >> 8;            // which batch of the pair
    const int ltid = tid & 255;
    const int b = 2 * blockIdx.x + half;
    const int c  = ltid & 7;              // k-chunk: ks [32c, 32c+32)
    const int rg = ltid >> 3;             // row group: rows [8rg, 8rg+8)

    // weights, rotated slot order to match the conflict-free h-read pattern:
    // w2[r][2j],[2j+1] = Whh[8rg+r][32c + 4*((j+c)&7) + {0..3}]
    v2f w2[8][16];
    #pragma unroll
    for (int r = 0; r < 8; ++r) {
        const float* wrow = Whh + (size_t)(8 * rg + r) * HH + 32 * c;
        #pragma unroll
        for (int j = 0; j < 8; ++j) {
            const int jj = (j + c) & 7;
            const float4 wv = *(const float4*)(wrow + 4 * jj);
            w2[r][2 * j]     = (v2f){wv.x, wv.y};
            w2[r][2 * j + 1] = (v2f){wv.z, wv.w};
        }
    }
    // Pin: asm results are non-rematerializable -> stay resident all loop.
    #pragma unroll
    for (int r = 0; r < 8; ++r) {
        asm volatile("" : "+v"(w2[r][0]),  "+v"(w2[r][1]),  "+v"(w2[r][2]),
                          "+v"(w2[r][3]),  "+v"(w2[r][4]),  "+v"(w2[r][5]),
                          "+v"(w2[r][6]),  "+v"(w2[r][7]),  "+v"(w2[r][8]),
                          "+v"(w2[r][9]),  "+v"(w2[r][10]), "+v"(w2[r][11]),
                          "+v"(w2[r][12]), "+v"(w2[r][13]), "+v"(w2[r][14]),
                          "+v"(w2[r][15]));
    }

    const int pb0 = c & 1, pb1 = (c >> 1) & 1, pb2 = (c >> 2) & 1;
    const int rl = 4 * pb2 + 2 * pb0 + pb1;   // bijection of c in [0,8)
    const int myrow = 8 * rg + rl;            // every lane owns one row

    const float alpha = 1.f / (1.f + __expf(-sigmas[myrow & 3]));

    // u-chunk staging geometry: lane piece p covers step-row p*4+sub, cols 4*col4.
    const int sub  = ltid >> 6;               // 0..3
    const int col4 = ltid & 63;               // float4 column
    const size_t ustride = (size_t)BB * HH;

    hbuf[half][0][ltid] = 0.0f;

    // prologue: stage chunk 0 -> buf 0 (compiler inserts the vmcnt wait)
    {
        #pragma unroll
        for (int p = 0; p < 4; ++p) {
            const int srow = 4 * p + sub;
            const float4 v = *(const float4*)(u + ((size_t)srow * BB + b) * HH + 4 * col4);
            *(float4*)&ubuf[half][0][srow][4 * col4] = v;
        }
    }

    float* hp = hist + (size_t)b * HH + myrow;       // -> hist[t=0]
    float hreg = 0.f;                                // h[myrow]

    __syncthreads();

#define K2_BODY(T, S, MBUF, DO_STAGE, NBUF)                                  \
    {                                                                        \
        const int cur = (T) & 1;                                             \
        const float uval = ubuf[half][MBUF][S][myrow];                       \
        float4 h4[8];                                                        \
        _Pragma("unroll")                                                    \
        for (int j = 0; j < 8; ++j)                                          \
            h4[j] = *(const float4*)&hbuf[half][cur][32 * c + 4 * ((j + c) & 7)]; \
        v2f aA[8], aB[8];                                                    \
        _Pragma("unroll")                                                    \
        for (int r = 0; r < 8; ++r) { aA[r] = (v2f)0.f; aB[r] = (v2f)0.f; }  \
        _Pragma("unroll")                                                    \
        for (int j = 0; j < 8; ++j) {                                        \
            const v2f hA = (v2f){h4[j].x, h4[j].y};                          \
            const v2f hB = (v2f){h4[j].z, h4[j].w};                          \
            _Pragma("unroll")                                                \
            for (int r = 0; r < 8; ++r) {                                    \
                aA[r] += w2[r][2 * j] * hA;                                  \
                aB[r] += w2[r][2 * j + 1] * hB;                              \
            }                                                                \
        }                                                                    \
        float s_[8];                                                         \
        _Pragma("unroll")                                                    \
        for (int r = 0; r < 8; ++r)                                          \
            s_[r] = (aA[r].x + aA[r].y) + (aB[r].x + aB[r].y);               \
        /* stage 1: xor7 (row_half_mirror), halve by pb2: keep 4 rows */     \
        float t1[4];                                                         \
        _Pragma("unroll")                                                    \
        for (int i = 0; i < 4; ++i) {                                        \
            const float g = pb2 ? s_[i] : s_[i + 4];                         \
            const float k = pb2 ? s_[i + 4] : s_[i];                         \
            t1[i] = k + dpp_mov_f<0x141>(g);                                 \
        }                                                                    \
        /* stage 2: xor1 (quad_perm 1,0,3,2), halve by pb0: keep 2 */        \
        float t2[2];                                                         \
        _Pragma("unroll")                                                    \
        for (int i = 0; i < 2; ++i) {                                        \
            const float g = pb0 ? t1[i] : t1[i + 2];                         \
            const float k = pb0 ? t1[i + 2] : t1[i];                         \
            t2[i] = k + dpp_mov_f<0xB1>(g);                                  \
        }                                                                    \
        /* stage 3: xor2 (quad_perm 2,3,0,1), halve by pb1: keep 1 */        \
        {                                                                    \
            const float g = pb1 ? t2[0] : t2[1];                             \
            const float k = pb1 ? t2[1] : t2[0];                             \
            const float sr = k + dpp_mov_f<0x4E>(g);                         \
            const float sin_ = sr + uval;                                    \
            *hp = hreg;                           /* pre-update h -> y[t] */ \
            hreg = hreg + alpha * (ftanh(sin_) - hreg);                      \
            hbuf[half][cur ^ 1][myrow] = hreg;                               \
        }                                                                    \
        hp += ustride;                                                       \
        if (DO_STAGE) {                                                      \
            /* write next u-chunk (loads issued at window start; vmcnt    */ \
            /* wait lands here, once per 16 steps)                        */ \
            *(float4*)&ubuf[half][NBUF][4 * 0 + sub][4 * col4] = st0;        \
            *(float4*)&ubuf[half][NBUF][4 * 1 + sub][4 * col4] = st1;        \
            *(float4*)&ubuf[half][NBUF][4 * 2 + sub][4 * col4] = st2;        \
            *(float4*)&ubuf[half][NBUF][4 * 3 + sub][4 * col4] = st3;        \
        }                                                                    \
        /* LDS-only drain + barrier: hist stores stay in flight */           \
        asm volatile("s_waitcnt lgkmcnt(0)\n\ts_barrier" ::: "memory");      \
    }

    for (int m = 0; m < NW; ++m) {
        const int mbuf = m & 1;
        const int nbuf = mbuf ^ 1;
        const bool more = (m + 1 < NW);
        // issue next-chunk global loads now; the asm "memory" barriers in the
        // bodies below keep them at this program point, giving ~15 steps of
        // latency slack before the DO_STAGE writes consume them.
        float4 st0, st1, st2, st3;
        if (more) {
            const size_t t0 = (size_t)(CHUNK * (m + 1));
            st0 = *(const float4*)(u + ((t0 + 4 * 0 + sub) * BB + b) * HH + 4 * col4);
            st1 = *(const float4*)(u + ((t0 + 4 * 1 + sub) * BB + b) * HH + 4 * col4);
            st2 = *(const float4*)(u + ((t0 + 4 * 2 + sub) * BB + b) * HH + 4 * col4);
            st3 = *(const float4*)(u + ((t0 + 4 * 3 + sub) * BB + b) * HH + 4 * col4);
        }
        #pragma unroll 4
        for (int s = 0; s < CHUNK; ++s) {
            const int t = CHUNK * m + s;
            const bool stage = (s == CHUNK - 1) && more;
            K2_BODY(t, s, mbuf, stage, nbuf)
        }
    }
#undef K2_BODY
}

// ---------------------------------------------------------------------------
// K3: y[e,o] = bout[o] + sum_k tanh(bhx[k] + sum_i hist[e,i]Whx[i,k]) * Wout[k,o]
// 32 rows/block, 256 threads. Same register-tiling scheme.
// ---------------------------------------------------------------------------
__global__ __launch_bounds__(256) void k3_y(
    const float* __restrict__ hist, const float* __restrict__ Whx,
    const float* __restrict__ bhx, const float* __restrict__ Wout,
    const float* __restrict__ bout, float* __restrict__ y)
{
    __shared__ float hs[32][HH];    // 32KB
    __shared__ float gs[32][DHH];   // 16KB
    const int tid = threadIdx.x;
    const size_t row0 = (size_t)blockIdx.x * 32;

    for (int v = tid; v < 32 * HH; v += 256) {
        int r = v >> 8, i = v & 255;
        hs[r][i] = hist[(row0 + r) * HH + i];
    }
    __syncthreads();

    // stage A: gs = tanh(hs @ Whx + bhx). cols aq+32j; rows 4ru..4ru+3. K=256
    {
        const int aq = tid & 31;
        const int ru = tid >> 5;
        v2f aA[4], aB[4];
        #pragma unroll
        for (int i = 0; i < 4; ++i) { aA[i] = (v2f)0.f; aB[i] = (v2f)0.f; }

        #pragma unroll
        for (int kc = 0; kc < 16; ++kc) {   // KC=16
            v2f wA[16], wB[16];
            #pragma unroll
            for (int k = 0; k < 16; ++k) {
                const float* wp = Whx + (size_t)(kc * 16 + k) * DHH + aq;
                wA[k] = (v2f){wp[0],  wp[32]};
                wB[k] = (v2f){wp[64], wp[96]};
            }
            #pragma unroll
            for (int k4 = 0; k4 < 4; ++k4) {
                float4 hv[4];
                #pragma unroll
                for (int i = 0; i < 4; ++i)
                    hv[i] = *(const float4*)&hs[4 * ru + i][kc * 16 + 4 * k4];
                #pragma unroll
                for (int i = 0; i < 4; ++i) {
                    #pragma unroll
                    for (int e = 0; e < 4; ++e) {
                        const float he = (e == 0) ? hv[i].x : (e == 1) ? hv[i].y
                                       : (e == 2) ? hv[i].z : hv[i].w;
                        const v2f hb = (v2f){he, he};
                        aA[i] += wA[4 * k4 + e] * hb;
                        aB[i] += wB[4 * k4 + e] * hb;
                    }
                }
            }
        }
        const float b0 = bhx[aq], b1 = bhx[aq + 32], b2 = bhx[aq + 64], b3 = bhx[aq + 96];
        #pragma unroll
        for (int i = 0; i < 4; ++i) {
            const int r = 4 * ru + i;
            gs[r][aq]      = ftanh(aA[i].x + b0);
            gs[r][aq + 32] = ftanh(aA[i].y + b1);
            gs[r][aq + 64] = ftanh(aB[i].x + b2);
            gs[r][aq + 96] = ftanh(aB[i].y + b3);
        }
    }
    __syncthreads();

    // stage B: y = gs @ Wout + bout. cols o2, o2+32; rows 4ru..4ru+3. K=128
    {
        const int o2 = tid & 31;
        const int ru = tid >> 5;
        v2f acc[4];
        #pragma unroll
        for (int i = 0; i < 4; ++i) acc[i] = (v2f)0.f;

        #pragma unroll
        for (int kc = 0; kc < 2; ++kc) {    // KC=64
            v2f w[64];
            #pragma unroll
            for (int k = 0; k < 64; ++k) {
                const float* wp = Wout + (size_t)(kc * 64 + k) * XDIM + o2;
                w[k] = (v2f){wp[0], wp[32]};
            }
            #pragma unroll
            for (int k4 = 0; k4 < 16; ++k4) {
                float4 gv[4];
                #pragma unroll
                for (int i = 0; i < 4; ++i)
                    gv[i] = *(const float4*)&gs[4 * ru + i][kc * 64 + 4 * k4];
                #pragma unroll
                for (int i = 0; i < 4; ++i) {
                    #pragma unroll
                    for (int e = 0; e < 4; ++e) {
                        const float ge = (e == 0) ? gv[i].x : (e == 1) ? gv[i].y
                                       : (e == 2) ? gv[i].z : gv[i].w;
                        acc[i] += w[4 * k4 + e] * (v2f){ge, ge};
                    }
                }
            }
        }
        const float b0 = bout[o2], b1 = bout[o2 + 32];
        #pragma unroll
        for (int i = 0; i < 4; ++i) {
            const size_t row = row0 + 4 * ru + i;
            y[row * XDIM + o2]      = acc[i].x + b0;
            y[row * XDIM + o2 + 32] = acc[i].y + b1;
        }
    }
}

extern "C" void kernel_launch(void* const* d_in, const int* in_sizes, int n_in,
                              void* d_out, int out_size, void* d_ws, size_t ws_size,
                              hipStream_t stream) {
    const float* x      = (const float*)d_in[0];
    const float* Wx     = (const float*)d_in[1];
    const float* bx     = (const float*)d_in[2];
    const float* Wih    = (const float*)d_in[3];
    const float* bih    = (const float*)d_in[4];
    const float* Whh    = (const float*)d_in[5];
    const float* bhh    = (const float*)d_in[6];
    const float* Whx    = (const float*)d_in[7];
    const float* bhx    = (const float*)d_in[8];
    const float* Wout   = (const float*)d_in[9];
    const float* bout   = (const float*)d_in[10];
    const float* sigmas = (const float*)d_in[11];
    float* y = (float*)d_out;

    float* u    = (float*)d_ws;                   // S*B*H floats = 128 MB
    float* hist = u + (size_t)SS * BB * HH;       // S*B*H floats = 128 MB

    k1_featu<<<(SS * BB) / 64, 256, 0, stream>>>(x, Wx, bx, Wih, bih, bhh, u);
    k2_rnn<<<BB / 2, 512, 0, stream>>>(u, Whh, sigmas, hist);
    k3_y<<<(SS * BB) / 32, 256, 0, stream>>>(hist, Whx, bhx, Wout, bout, y);
}

// Round 16
// 1956.300 us; speedup vs baseline: 10.3472x; 10.3472x over previous
//
#include <hip/hip_runtime.h>
#include <math.h>

#define SS 2048
#define BB 64
#define XDIM 64
#define DXF 128
#define HH 256
#define DHH 128
#define CHUNK 16
#define NW (SS / CHUNK)   // 128 windows

typedef float v2f __attribute__((ext_vector_type(2)));

// tanh(x) = 1 - 2/(exp(2x)+1); __expf -> v_exp_f32, ~1e-6 abs err, saturates correctly.
__device__ __forceinline__ float ftanh(float x) {
    float e = __expf(2.0f * x);
    return 1.0f - 2.0f / (e + 1.0f);
}

template <int CTRL>
__device__ __forceinline__ float dpp_mov_f(float x) {
    return __int_as_float(__builtin_amdgcn_update_dpp(
        0, __float_as_int(x), CTRL, 0xF, 0xF, true));
}

// ---------------------------------------------------------------------------
// K1: u[e,i] = bih[i]+bhh[i] + sum_j tanh(bx[j] + sum_m x[e,m]Wx[m,j]) * Wih[i,j]
// 64 rows/block, 256 threads. Register tiles: 4 cols x 4 rows, float4 LDS reads.
// ---------------------------------------------------------------------------
__global__ __launch_bounds__(256) void k1_featu(
    const float* __restrict__ x, const float* __restrict__ Wx,
    const float* __restrict__ bx, const float* __restrict__ Wih,
    const float* __restrict__ bih, const float* __restrict__ bhh,
    float* __restrict__ u)
{
    __shared__ float xs[64][XDIM];   // 16KB
    __shared__ float fs[64][DXF];    // 32KB
    const int tid = threadIdx.x;
    const size_t row0 = (size_t)blockIdx.x * 64;

    for (int v = tid; v < 64 * XDIM; v += 256) {
        int r = v >> 6, m = v & 63;
        xs[r][m] = x[(row0 + r) * XDIM + m];
    }
    __syncthreads();

    // stage 2: fs = tanh(xs @ Wx + bx). cols: cq+32j; rows: 8ru..8ru+7
    {
        const int cq = tid & 31;
        const int ru = tid >> 5;
        v2f aA[2][4], aB[2][4];
        #pragma unroll
        for (int g = 0; g < 2; ++g)
            #pragma unroll
            for (int i = 0; i < 4; ++i) { aA[g][i] = (v2f)0.f; aB[g][i] = (v2f)0.f; }

        #pragma unroll
        for (int kc = 0; kc < 4; ++kc) {          // K=64, KC=16
            v2f wA[16], wB[16];
            #pragma unroll
            for (int k = 0; k < 16; ++k) {
                const float* wp = Wx + (kc * 16 + k) * DXF + cq;
                wA[k] = (v2f){wp[0],  wp[32]};
                wB[k] = (v2f){wp[64], wp[96]};
            }
            #pragma unroll
            for (int g = 0; g < 2; ++g) {
                const int rb = 8 * ru + 4 * g;
                #pragma unroll
                for (int k4 = 0; k4 < 4; ++k4) {
                    float4 xv[4];
                    #pragma unroll
                    for (int i = 0; i < 4; ++i)
                        xv[i] = *(const float4*)&xs[rb + i][kc * 16 + 4 * k4];
                    #pragma unroll
                    for (int i = 0; i < 4; ++i) {
                        #pragma unroll
                        for (int e = 0; e < 4; ++e) {
                            const float xe = (e == 0) ? xv[i].x : (e == 1) ? xv[i].y
                                           : (e == 2) ? xv[i].z : xv[i].w;
                            const v2f xb = (v2f){xe, xe};
                            aA[g][i] += wA[4 * k4 + e] * xb;
                            aB[g][i] += wB[4 * k4 + e] * xb;
                        }
                    }
                }
            }
        }
        const float b0 = bx[cq], b1 = bx[cq + 32], b2 = bx[cq + 64], b3 = bx[cq + 96];
        #pragma unroll
        for (int g = 0; g < 2; ++g)
            #pragma unroll
            for (int i = 0; i < 4; ++i) {
                const int r = 8 * ru + 4 * g + i;
                fs[r][cq]      = ftanh(aA[g][i].x + b0);
                fs[r][cq + 32] = ftanh(aA[g][i].y + b1);
                fs[r][cq + 64] = ftanh(aB[g][i].x + b2);
                fs[r][cq + 96] = ftanh(aB[g][i].y + b3);
            }
    }
    __syncthreads();

    // stage 3: u = fs @ Wih^T + bih + bhh. cols q4+64j; rows 16rq..16rq+15
    {
        const int q4 = tid & 63;
        const int rq = tid >> 6;
        v2f aA[4][4], aB[4][4];
        #pragma unroll
        for (int g = 0; g < 4; ++g)
            #pragma unroll
            for (int i = 0; i < 4; ++i) { aA[g][i] = (v2f)0.f; aB[g][i] = (v2f)0.f; }

        #pragma unroll
        for (int kc = 0; kc < 8; ++kc) {          // K=128, KC=16
            v2f wA[16], wB[16];
            #pragma unroll
            for (int k4 = 0; k4 < 4; ++k4) {
                const float4 w0 = *(const float4*)(Wih + (size_t)(q4      ) * DXF + kc * 16 + 4 * k4);
                const float4 w1 = *(const float4*)(Wih + (size_t)(q4 +  64) * DXF + kc * 16 + 4 * k4);
                const float4 w2 = *(const float4*)(Wih + (size_t)(q4 + 128) * DXF + kc * 16 + 4 * k4);
                const float4 w3 = *(const float4*)(Wih + (size_t)(q4 + 192) * DXF + kc * 16 + 4 * k4);
                wA[4 * k4 + 0] = (v2f){w0.x, w1.x}; wA[4 * k4 + 1] = (v2f){w0.y, w1.y};
                wA[4 * k4 + 2] = (v2f){w0.z, w1.z}; wA[4 * k4 + 3] = (v2f){w0.w, w1.w};
                wB[4 * k4 + 0] = (v2f){w2.x, w3.x}; wB[4 * k4 + 1] = (v2f){w2.y, w3.y};
                wB[4 * k4 + 2] = (v2f){w2.z, w3.z}; wB[4 * k4 + 3] = (v2f){w2.w, w3.w};
            }
            #pragma unroll
            for (int g = 0; g < 4; ++g) {
                const int rb = 16 * rq + 4 * g;
                #pragma unroll
                for (int k4 = 0; k4 < 4; ++k4) {
                    float4 fv[4];
                    #pragma unroll
                    for (int i = 0; i < 4; ++i)
                        fv[i] = *(const float4*)&fs[rb + i][kc * 16 + 4 * k4];
                    #pragma unroll
                    for (int i = 0; i < 4; ++i) {
                        #pragma unroll
                        for (int e = 0; e < 4; ++e) {
                            const float fe = (e == 0) ? fv[i].x : (e == 1) ? fv[i].y
                                           : (e == 2) ? fv[i].z : fv[i].w;
                            const v2f fb = (v2f){fe, fe};
                            aA[g][i] += wA[4 * k4 + e] * fb;
                            aB[g][i] += wB[4 * k4 + e] * fb;
                        }
                    }
                }
            }
        }
        const float b0 = bih[q4]       + bhh[q4];
        const float b1 = bih[q4 + 64]  + bhh[q4 + 64];
        const float b2 = bih[q4 + 128] + bhh[q4 + 128];
        const float b3 = bih[q4 + 192] + bhh[q4 + 192];
        #pragma unroll
        for (int g = 0; g < 4; ++g)
            #pragma unroll
            for (int i = 0; i < 4; ++i) {
                const size_t row = row0 + 16 * rq + 4 * g + i;
                u[row * HH + q4]       = aA[g][i].x + b0;
                u[row * HH + q4 + 64]  = aA[g][i].y + b1;
                u[row * HH + q4 + 128] = aB[g][i].x + b2;
                u[row * HH + q4 + 192] = aB[g][i].y + b3;
            }
    }
}

// ---------------------------------------------------------------------------
// K2: sequential recurrence. R21: 1024 threads (16 waves), ONE batch/block,
// grid = 64. Thread (rg = tid>>4, c = tid&15) owns rows [4rg,4rg+4) x ks
// [16c,16c+16) = 64 weight floats.
//
// R15/R20 post-mortem: with 512-thr blocks the backend pins the unified
// register budget at 128 (two different waves_per_eu settings both gave
// VGPR_Count=128) -> the 256-float weight set spilled to scratch
// (WRITE_SIZE +220MB, VALUBusy 1%, 19.5ms). Fix: geometry that NEEDS only
// ~110 regs. waves_per_eu(4,4) at 1024 thr = the historically-honored
// config (R2-R5 era) giving exactly the 128-reg budget.
//
// Mechanisms kept:
//   * chunked-u: 16-step windows, double-buffered LDS; 1 global_load_dwordx4
//     + 1 ds_write per thread per window (~15 steps HBM slack); per-step u
//     is one broadcast ds_read_b32. No global load on the per-step chain.
//   * 16 waves for TLP (R6-class), but HALF R6's LDS-read count:
//     h stored DE-INTERLEAVED: h[i] at pos 64*((i>>2)&3) + 4*(i>>4) + (i&3),
//     so lane c's slot j is a b128 at pos 64j+4c -> 16 lanes span 64
//     consecutive floats = 2 lanes/bank (free, m136); rg-groups broadcast.
//     64 b128-instr/CU/step vs R6's 128.
//   * reduce over 16 lanes: value-halving xor8 (row_ror:8=0x128, verified
//     R7/R8) by pb3, xor1 (0xB1) by pb0, then full-add xor2 (0x4E) and
//     full-add xor4 (ds_swizzle 0x101F, BitMode xor encoding per ISA doc).
//     Every lane ends with the full sum of row 4rg + 2*pb3 + pb0 (x4
//     replicas); tail computed uniformly by all, stored by c&6==0 owners.
// ---------------------------------------------------------------------------
__global__ __launch_bounds__(1024)
__attribute__((amdgpu_waves_per_eu(4, 4)))
void k2_rnn(
    const float* __restrict__ u, const float* __restrict__ Whh,
    const float* __restrict__ sigmas, float* __restrict__ hist)
{
    __shared__ float hbuf[2][HH];          // de-interleaved, 2KB
    __shared__ float ubuf[2][CHUNK][HH];   // [buf][step][row] 32KB
    const int tid = threadIdx.x;
    const int b = blockIdx.x;
    const int c  = tid & 15;               // k-chunk: ks [16c, 16c+16)
    const int rg = tid >> 4;               // row group: rows [4rg, 4rg+4)

    // weights: w2[r][2j]   = {Whh[4rg+r][16c+4j],   [16c+4j+1]}
    //          w2[r][2j+1] = {Whh[4rg+r][16c+4j+2], [16c+4j+3]}
    v2f w2[4][8];
    #pragma unroll
    for (int r = 0; r < 4; ++r) {
        const float* wrow = Whh + (size_t)(4 * rg + r) * HH + 16 * c;
        #pragma unroll
        for (int j = 0; j < 4; ++j) {
            const float4 wv = *(const float4*)(wrow + 4 * j);
            w2[r][2 * j]     = (v2f){wv.x, wv.y};
            w2[r][2 * j + 1] = (v2f){wv.z, wv.w};
        }
    }
    // Pin: asm results are non-rematerializable -> stay resident all loop.
    #pragma unroll
    for (int r = 0; r < 4; r += 2) {
        asm volatile("" : "+v"(w2[r][0]),     "+v"(w2[r][1]),     "+v"(w2[r][2]),     "+v"(w2[r][3]),
                          "+v"(w2[r][4]),     "+v"(w2[r][5]),     "+v"(w2[r][6]),     "+v"(w2[r][7]),
                          "+v"(w2[r + 1][0]), "+v"(w2[r + 1][1]), "+v"(w2[r + 1][2]), "+v"(w2[r + 1][3]),
                          "+v"(w2[r + 1][4]), "+v"(w2[r + 1][5]), "+v"(w2[r + 1][6]), "+v"(w2[r + 1][7]));
    }

    const int pb0 = c & 1;
    const int pb3 = (c >> 3) & 1;
    const int rl = 2 * pb3 + pb0;             // local row after value-halving
    const int myrow = 4 * rg + rl;            // 4 replica lanes per row
    const bool own = ((c & 6) == 0);          // one store-owner per replica set

    const float alpha = 1.f / (1.f + __expf(-sigmas[myrow & 3]));

    // de-interleaved position of myrow for the hbuf store
    const int wpos = 64 * ((myrow >> 2) & 3) + 4 * (myrow >> 4) + (myrow & 3);

    // u staging geometry: thread covers step-row (tid>>6), float4 col (tid&63)
    const int srow = tid >> 6;                // 0..15
    const int col4 = tid & 63;                // 0..63
    const size_t ustride = (size_t)BB * HH;

    if (tid < HH) hbuf[0][tid] = 0.0f;        // zeros are layout-invariant

    // prologue: stage chunk 0 -> buf 0 (compiler inserts the vmcnt wait)
    {
        const float4 v = *(const float4*)(u + ((size_t)srow * BB + b) * HH + 4 * col4);
        *(float4*)&ubuf[0][srow][4 * col4] = v;
    }

    float* hp = hist + (size_t)b * HH + myrow;       // -> hist[t=0]
    float hreg = 0.f;                                // h[myrow] (all replicas)

    __syncthreads();

#define K2_BODY(T, S, MBUF, DO_STAGE, NBUF)                                  \
    {                                                                        \
        const int cur = (T) & 1;                                             \
        const float uval = ubuf[MBUF][S][myrow];                             \
        float4 h4[4];                                                        \
        _Pragma("unroll")                                                    \
        for (int j = 0; j < 4; ++j)                                          \
            h4[j] = *(const float4*)&hbuf[cur][64 * j + 4 * c];              \
        v2f acc[4];                                                          \
        _Pragma("unroll")                                                    \
        for (int r = 0; r < 4; ++r) acc[r] = (v2f)0.f;                       \
        _Pragma("unroll")                                                    \
        for (int j = 0; j < 4; ++j) {                                        \
            const v2f hA = (v2f){h4[j].x, h4[j].y};                          \
            const v2f hB = (v2f){h4[j].z, h4[j].w};                          \
            _Pragma("unroll")                                                \
            for (int r = 0; r < 4; ++r) {                                    \
                acc[r] += w2[r][2 * j] * hA;                                 \
                acc[r] += w2[r][2 * j + 1] * hB;                             \
            }                                                                \
        }                                                                    \
        float s_[4];                                                         \
        _Pragma("unroll")                                                    \
        for (int r = 0; r < 4; ++r) s_[r] = acc[r].x + acc[r].y;             \
        /* stage 1: xor8 (row_ror:8), halve by pb3: keep 2 rows */           \
        float t1[2];                                                         \
        _Pragma("unroll")                                                    \
        for (int i = 0; i < 2; ++i) {                                        \
            const float g = pb3 ? s_[i] : s_[i + 2];                         \
            const float k = pb3 ? s_[i + 2] : s_[i];                         \
            t1[i] = k + dpp_mov_f<0x128>(g);                                 \
        }                                                                    \
        /* stage 2: xor1 (quad_perm 1,0,3,2), halve by pb0: keep 1 */        \
        float sr;                                                            \
        {                                                                    \
            const float g = pb0 ? t1[0] : t1[1];                             \
            const float k = pb0 ? t1[1] : t1[0];                             \
            sr = k + dpp_mov_f<0xB1>(g);                                     \
        }                                                                    \
        /* stage 3: xor2 (quad_perm 2,3,0,1), full add */                    \
        sr += dpp_mov_f<0x4E>(sr);                                           \
        /* stage 4: xor4 via ds_swizzle (BitMode xor=4) */                   \
        sr += __int_as_float(__builtin_amdgcn_ds_swizzle(                    \
                  __float_as_int(sr), 0x101F));                              \
        {                                                                    \
            const float sin_ = sr + uval;                                    \
            const float hnew = hreg + alpha * (ftanh(sin_) - hreg);          \
            if (own) {                                                       \
                *hp = hreg;                       /* pre-update h -> y[t] */ \
                hbuf[cur ^ 1][wpos] = hnew;                                  \
            }                                                                \
            hreg = hnew;                                                     \
        }                                                                    \
        hp += ustride;                                                       \
        if (DO_STAGE) {                                                      \
            /* write next u-chunk (load issued at window start; vmcnt     */ \
            /* wait lands here, once per 16 steps)                        */ \
            *(float4*)&ubuf[NBUF][srow][4 * col4] = stv;                     \
        }                                                                    \
        /* LDS-only drain + barrier: hist stores stay in flight */           \
        asm volatile("s_waitcnt lgkmcnt(0)\n\ts_barrier" ::: "memory");      \
    }

    for (int m = 0; m < NW; ++m) {
        const int mbuf = m & 1;
        const int nbuf = mbuf ^ 1;
        const bool more = (m + 1 < NW);
        // issue next-chunk global load now; the asm "memory" barriers in the
        // bodies below keep it at this program point, giving ~15 steps of
        // latency slack before the DO_STAGE write consumes it.
        float4 stv;
        if (more) {
            const size_t t0 = (size_t)(CHUNK * (m + 1));
            stv = *(const float4*)(u + ((t0 + srow) * BB + b) * HH + 4 * col4);
        }
        #pragma unroll 4
        for (int s = 0; s < CHUNK; ++s) {
            const int t = CHUNK * m + s;
            const bool stage = (s == CHUNK - 1) && more;
            K2_BODY(t, s, mbuf, stage, nbuf)
        }
    }
#undef K2_BODY
}

// ---------------------------------------------------------------------------
// K3: y[e,o] = bout[o] + sum_k tanh(bhx[k] + sum_i hist[e,i]Whx[i,k]) * Wout[k,o]
// 32 rows/block, 256 threads. Same register-tiling scheme.
// ---------------------------------------------------------------------------
__global__ __launch_bounds__(256) void k3_y(
    const float* __restrict__ hist, const float* __restrict__ Whx,
    const float* __restrict__ bhx, const float* __restrict__ Wout,
    const float* __restrict__ bout, float* __restrict__ y)
{
    __shared__ float hs[32][HH];    // 32KB
    __shared__ float gs[32][DHH];   // 16KB
    const int tid = threadIdx.x;
    const size_t row0 = (size_t)blockIdx.x * 32;

    for (int v = tid; v < 32 * HH; v += 256) {
        int r = v >> 8, i = v & 255;
        hs[r][i] = hist[(row0 + r) * HH + i];
    }
    __syncthreads();

    // stage A: gs = tanh(hs @ Whx + bhx). cols aq+32j; rows 4ru..4ru+3. K=256
    {
        const int aq = tid & 31;
        const int ru = tid >> 5;
        v2f aA[4], aB[4];
        #pragma unroll
        for (int i = 0; i < 4; ++i) { aA[i] = (v2f)0.f; aB[i] = (v2f)0.f; }

        #pragma unroll
        for (int kc = 0; kc < 16; ++kc) {   // KC=16
            v2f wA[16], wB[16];
            #pragma unroll
            for (int k = 0; k < 16; ++k) {
                const float* wp = Whx + (size_t)(kc * 16 + k) * DHH + aq;
                wA[k] = (v2f){wp[0],  wp[32]};
                wB[k] = (v2f){wp[64], wp[96]};
            }
            #pragma unroll
            for (int k4 = 0; k4 < 4; ++k4) {
                float4 hv[4];
                #pragma unroll
                for (int i = 0; i < 4; ++i)
                    hv[i] = *(const float4*)&hs[4 * ru + i][kc * 16 + 4 * k4];
                #pragma unroll
                for (int i = 0; i < 4; ++i) {
                    #pragma unroll
                    for (int e = 0; e < 4; ++e) {
                        const float he = (e == 0) ? hv[i].x : (e == 1) ? hv[i].y
                                       : (e == 2) ? hv[i].z : hv[i].w;
                        const v2f hb = (v2f){he, he};
                        aA[i] += wA[4 * k4 + e] * hb;
                        aB[i] += wB[4 * k4 + e] * hb;
                    }
                }
            }
        }
        const float b0 = bhx[aq], b1 = bhx[aq + 32], b2 = bhx[aq + 64], b3 = bhx[aq + 96];
        #pragma unroll
        for (int i = 0; i < 4; ++i) {
            const int r = 4 * ru + i;
            gs[r][aq]      = ftanh(aA[i].x + b0);
            gs[r][aq + 32] = ftanh(aA[i].y + b1);
            gs[r][aq + 64] = ftanh(aB[i].x + b2);
            gs[r][aq + 96] = ftanh(aB[i].y + b3);
        }
    }
    __syncthreads();

    // stage B: y = gs @ Wout + bout. cols o2, o2+32; rows 4ru..4ru+3. K=128
    {
        const int o2 = tid & 31;
        const int ru = tid >> 5;
        v2f acc[4];
        #pragma unroll
        for (int i = 0; i < 4; ++i) acc[i] = (v2f)0.f;

        #pragma unroll
        for (int kc = 0; kc < 2; ++kc) {    // KC=64
            v2f w[64];
            #pragma unroll
            for (int k = 0; k < 64; ++k) {
                const float* wp = Wout + (size_t)(kc * 64 + k) * XDIM + o2;
                w[k] = (v2f){wp[0], wp[32]};
            }
            #pragma unroll
            for (int k4 = 0; k4 < 16; ++k4) {
                float4 gv[4];
                #pragma unroll
                for (int i = 0; i < 4; ++i)
                    gv[i] = *(const float4*)&gs[4 * ru + i][kc * 64 + 4 * k4];
                #pragma unroll
                for (int i = 0; i < 4; ++i) {
                    #pragma unroll
                    for (int e = 0; e < 4; ++e) {
                        const float ge = (e == 0) ? gv[i].x : (e == 1) ? gv[i].y
                                       : (e == 2) ? gv[i].z : gv[i].w;
                        acc[i] += w[4 * k4 + e] * (v2f){ge, ge};
                    }
                }
            }
        }
        const float b0 = bout[o2], b1 = bout[o2 + 32];
        #pragma unroll
        for (int i = 0; i < 4; ++i) {
            const size_t row = row0 + 4 * ru + i;
            y[row * XDIM + o2]      = acc[i].x + b0;
            y[row * XDIM + o2 + 32] = acc[i].y + b1;
        }
    }
}

extern "C" void kernel_launch(void* const* d_in, const int* in_sizes, int n_in,
                              void* d_out, int out_size, void* d_ws, size_t ws_size,
                              hipStream_t stream) {
    const float* x      = (const float*)d_in[0];
    const float* Wx     = (const float*)d_in[1];
    const float* bx     = (const float*)d_in[2];
    const float* Wih    = (const float*)d_in[3];
    const float* bih    = (const float*)d_in[4];
    const float* Whh    = (const float*)d_in[5];
    const float* bhh    = (const float*)d_in[6];
    const float* Whx    = (const float*)d_in[7];
    const float* bhx    = (const float*)d_in[8];
    const float* Wout   = (const float*)d_in[9];
    const float* bout   = (const float*)d_in[10];
    const float* sigmas = (const float*)d_in[11];
    float* y = (float*)d_out;

    float* u    = (float*)d_ws;                   // S*B*H floats = 128 MB
    float* hist = u + (size_t)SS * BB * HH;       // S*B*H floats = 128 MB

    k1_featu<<<(SS * BB) / 64, 256, 0, stream>>>(x, Wx, bx, Wih, bih, bhh, u);
    k2_rnn<<<BB, 1024, 0, stream>>>(u, Whh, sigmas, hist);
    k3_y<<<(SS * BB) / 32, 256, 0, stream>>>(hist, Whx, bhx, Wout, bout, y);
}

// Round 17
// 1804.122 us; speedup vs baseline: 11.2200x; 1.0844x over previous
//
#include <hip/hip_runtime.h>
#include <math.h>

#define SS 2048
#define BB 64
#define XDIM 64
#define DXF 128
#define HH 256
#define DHH 128
#define CHUNK 16
#define NW (SS / CHUNK)   // 128 windows

typedef float v2f __attribute__((ext_vector_type(2)));

// tanh(x) = 1 - 2/(exp(2x)+1); __expf -> v_exp_f32, ~1e-6 abs err, saturates correctly.
__device__ __forceinline__ float ftanh(float x) {
    float e = __expf(2.0f * x);
    return 1.0f - 2.0f / (e + 1.0f);
}

template <int CTRL>
__device__ __forceinline__ float dpp_mov_f(float x) {
    return __int_as_float(__builtin_amdgcn_update_dpp(
        0, __float_as_int(x), CTRL, 0xF, 0xF, true));
}

// ---------------------------------------------------------------------------
// K1: u[e,i] = bih[i]+bhh[i] + sum_j tanh(bx[j] + sum_m x[e,m]Wx[m,j]) * Wih[i,j]
// 64 rows/block, 256 threads. Register tiles: 4 cols x 4 rows, float4 LDS reads.
// ---------------------------------------------------------------------------
__global__ __launch_bounds__(256) void k1_featu(
    const float* __restrict__ x, const float* __restrict__ Wx,
    const float* __restrict__ bx, const float* __restrict__ Wih,
    const float* __restrict__ bih, const float* __restrict__ bhh,
    float* __restrict__ u)
{
    __shared__ float xs[64][XDIM];   // 16KB
    __shared__ float fs[64][DXF];    // 32KB
    const int tid = threadIdx.x;
    const size_t row0 = (size_t)blockIdx.x * 64;

    for (int v = tid; v < 64 * XDIM; v += 256) {
        int r = v >> 6, m = v & 63;
        xs[r][m] = x[(row0 + r) * XDIM + m];
    }
    __syncthreads();

    // stage 2: fs = tanh(xs @ Wx + bx). cols: cq+32j; rows: 8ru..8ru+7
    {
        const int cq = tid & 31;
        const int ru = tid >> 5;
        v2f aA[2][4], aB[2][4];
        #pragma unroll
        for (int g = 0; g < 2; ++g)
            #pragma unroll
            for (int i = 0; i < 4; ++i) { aA[g][i] = (v2f)0.f; aB[g][i] = (v2f)0.f; }

        #pragma unroll
        for (int kc = 0; kc < 4; ++kc) {          // K=64, KC=16
            v2f wA[16], wB[16];
            #pragma unroll
            for (int k = 0; k < 16; ++k) {
                const float* wp = Wx + (kc * 16 + k) * DXF + cq;
                wA[k] = (v2f){wp[0],  wp[32]};
                wB[k] = (v2f){wp[64], wp[96]};
            }
            #pragma unroll
            for (int g = 0; g < 2; ++g) {
                const int rb = 8 * ru + 4 * g;
                #pragma unroll
                for (int k4 = 0; k4 < 4; ++k4) {
                    float4 xv[4];
                    #pragma unroll
                    for (int i = 0; i < 4; ++i)
                        xv[i] = *(const float4*)&xs[rb + i][kc * 16 + 4 * k4];
                    #pragma unroll
                    for (int i = 0; i < 4; ++i) {
                        #pragma unroll
                        for (int e = 0; e < 4; ++e) {
                            const float xe = (e == 0) ? xv[i].x : (e == 1) ? xv[i].y
                                           : (e == 2) ? xv[i].z : xv[i].w;
                            const v2f xb = (v2f){xe, xe};
                            aA[g][i] += wA[4 * k4 + e] * xb;
                            aB[g][i] += wB[4 * k4 + e] * xb;
                        }
                    }
                }
            }
        }
        const float b0 = bx[cq], b1 = bx[cq + 32], b2 = bx[cq + 64], b3 = bx[cq + 96];
        #pragma unroll
        for (int g = 0; g < 2; ++g)
            #pragma unroll
            for (int i = 0; i < 4; ++i) {
                const int r = 8 * ru + 4 * g + i;
                fs[r][cq]      = ftanh(aA[g][i].x + b0);
                fs[r][cq + 32] = ftanh(aA[g][i].y + b1);
                fs[r][cq + 64] = ftanh(aB[g][i].x + b2);
                fs[r][cq + 96] = ftanh(aB[g][i].y + b3);
            }
    }
    __syncthreads();

    // stage 3: u = fs @ Wih^T + bih + bhh. cols q4+64j; rows 16rq..16rq+15
    {
        const int q4 = tid & 63;
        const int rq = tid >> 6;
        v2f aA[4][4], aB[4][4];
        #pragma unroll
        for (int g = 0; g < 4; ++g)
            #pragma unroll
            for (int i = 0; i < 4; ++i) { aA[g][i] = (v2f)0.f; aB[g][i] = (v2f)0.f; }

        #pragma unroll
        for (int kc = 0; kc < 8; ++kc) {          // K=128, KC=16
            v2f wA[16], wB[16];
            #pragma unroll
            for (int k4 = 0; k4 < 4; ++k4) {
                const float4 w0 = *(const float4*)(Wih + (size_t)(q4      ) * DXF + kc * 16 + 4 * k4);
                const float4 w1 = *(const float4*)(Wih + (size_t)(q4 +  64) * DXF + kc * 16 + 4 * k4);
                const float4 w2 = *(const float4*)(Wih + (size_t)(q4 + 128) * DXF + kc * 16 + 4 * k4);
                const float4 w3 = *(const float4*)(Wih + (size_t)(q4 + 192) * DXF + kc * 16 + 4 * k4);
                wA[4 * k4 + 0] = (v2f){w0.x, w1.x}; wA[4 * k4 + 1] = (v2f){w0.y, w1.y};
                wA[4 * k4 + 2] = (v2f){w0.z, w1.z}; wA[4 * k4 + 3] = (v2f){w0.w, w1.w};
                wB[4 * k4 + 0] = (v2f){w2.x, w3.x}; wB[4 * k4 + 1] = (v2f){w2.y, w3.y};
                wB[4 * k4 + 2] = (v2f){w2.z, w3.z}; wB[4 * k4 + 3] = (v2f){w2.w, w3.w};
            }
            #pragma unroll
            for (int g = 0; g < 4; ++g) {
                const int rb = 16 * rq + 4 * g;
                #pragma unroll
                for (int k4 = 0; k4 < 4; ++k4) {
                    float4 fv[4];
                    #pragma unroll
                    for (int i = 0; i < 4; ++i)
                        fv[i] = *(const float4*)&fs[rb + i][kc * 16 + 4 * k4];
                    #pragma unroll
                    for (int i = 0; i < 4; ++i) {
                        #pragma unroll
                        for (int e = 0; e < 4; ++e) {
                            const float fe = (e == 0) ? fv[i].x : (e == 1) ? fv[i].y
                                           : (e == 2) ? fv[i].z : fv[i].w;
                            const v2f fb = (v2f){fe, fe};
                            aA[g][i] += wA[4 * k4 + e] * fb;
                            aB[g][i] += wB[4 * k4 + e] * fb;
                        }
                    }
                }
            }
        }
        const float b0 = bih[q4]       + bhh[q4];
        const float b1 = bih[q4 + 64]  + bhh[q4 + 64];
        const float b2 = bih[q4 + 128] + bhh[q4 + 128];
        const float b3 = bih[q4 + 192] + bhh[q4 + 192];
        #pragma unroll
        for (int g = 0; g < 4; ++g)
            #pragma unroll
            for (int i = 0; i < 4; ++i) {
                const size_t row = row0 + 16 * rq + 4 * g + i;
                u[row * HH + q4]       = aA[g][i].x + b0;
                u[row * HH + q4 + 64]  = aA[g][i].y + b1;
                u[row * HH + q4 + 128] = aB[g][i].x + b2;
                u[row * HH + q4 + 192] = aB[g][i].y + b3;
            }
    }
}

// ---------------------------------------------------------------------------
// K2: sequential recurrence. R22: 512 threads (8 waves), one batch/block,
// grid = 64. Thread (rg = tid>>4 in [0,32), c = tid&15) owns rows
// [8rg,8rg+8) x ks [16c,16c+16) = 128 weight floats (64 VGPRs).
//
// R21 post-mortem: best yet (1435us) but halving LDS instrs bought only 5%.
// Invariant across ALL 16-wave variants: ~1700cy/step regardless of LDS
// instruction count (128/80/32 reads) or reduce depth; VALU issue only
// ~300cy/SIMD. The remaining wave-count-dependent term is the per-step
// BARRIER/resync itself (~16 waves x ~80cy wake ~= 1300cy). Test: halve the
// barrier population (8 waves) while keeping every proven mechanism:
//   * chunked-u double-buffered LDS staging (u never on the step chain)
//   * de-interleaved h layout: h[i] at pos 64*((i>>2)&3)+4*(i>>4)+(i&3);
//     lane c reads 4x b128 at pos 64j+4c (2-way bank = free class)
//   * value-halving reduce, R21's verified stage set + one more halving:
//     xor8 (row_ror:8 0x128, pb3), xor1 (0xB1, pb0), xor2 (0x4E, pb1),
//     full-add xor4 (ds_swizzle 0x101F). rl = 4*pb3+2*pb0+pb1; replicas at
//     c and c^4; owner c&4==0.
//   * lgkm-only barrier (hist stores stay in flight).
// Register budget: 512-thr blocks get 128 VGPRs (R15/R20 measured, attrs
// ignored); live ~= 64 weights + ~55 working = fits. Spill discriminator:
// WRITE_SIZE must stay ~131MB (R15's spill showed +220MB).
// ---------------------------------------------------------------------------
__global__ __launch_bounds__(512)
void k2_rnn(
    const float* __restrict__ u, const float* __restrict__ Whh,
    const float* __restrict__ sigmas, float* __restrict__ hist)
{
    __shared__ float hbuf[2][HH];          // de-interleaved, 2KB
    __shared__ float ubuf[2][CHUNK][HH];   // [buf][step][row] 32KB
    const int tid = threadIdx.x;
    const int b = blockIdx.x;
    const int c  = tid & 15;               // k-chunk: ks [16c, 16c+16)
    const int rg = tid >> 4;               // row group: rows [8rg, 8rg+8)

    // weights: w2[r][2j]   = {Whh[8rg+r][16c+4j],   [16c+4j+1]}
    //          w2[r][2j+1] = {Whh[8rg+r][16c+4j+2], [16c+4j+3]}
    v2f w2[8][8];
    #pragma unroll
    for (int r = 0; r < 8; ++r) {
        const float* wrow = Whh + (size_t)(8 * rg + r) * HH + 16 * c;
        #pragma unroll
        for (int j = 0; j < 4; ++j) {
            const float4 wv = *(const float4*)(wrow + 4 * j);
            w2[r][2 * j]     = (v2f){wv.x, wv.y};
            w2[r][2 * j + 1] = (v2f){wv.z, wv.w};
        }
    }
    // Pin: asm results are non-rematerializable -> stay resident all loop.
    #pragma unroll
    for (int r = 0; r < 8; r += 2) {
        asm volatile("" : "+v"(w2[r][0]),     "+v"(w2[r][1]),     "+v"(w2[r][2]),     "+v"(w2[r][3]),
                          "+v"(w2[r][4]),     "+v"(w2[r][5]),     "+v"(w2[r][6]),     "+v"(w2[r][7]),
                          "+v"(w2[r + 1][0]), "+v"(w2[r + 1][1]), "+v"(w2[r + 1][2]), "+v"(w2[r + 1][3]),
                          "+v"(w2[r + 1][4]), "+v"(w2[r + 1][5]), "+v"(w2[r + 1][6]), "+v"(w2[r + 1][7]));
    }

    const int pb0 = c & 1;
    const int pb1 = (c >> 1) & 1;
    const int pb3 = (c >> 3) & 1;
    const int rl = 4 * pb3 + 2 * pb0 + pb1;   // local row after halvings
    const int myrow = 8 * rg + rl;            // 2 replica lanes (c, c^4)
    const bool own = ((c & 4) == 0);          // one store-owner per row

    const float alpha = 1.f / (1.f + __expf(-sigmas[myrow & 3]));

    // de-interleaved position of myrow for the hbuf store
    const int wpos = 64 * ((myrow >> 2) & 3) + 4 * (myrow >> 4) + (myrow & 3);

    // u staging geometry: float4-index space [0,1024) covered twice:
    // p = tid + 512k -> step s = p>>6, float4 col c4 = p&63
    const int s0 = tid >> 6,          c40 = tid & 63;
    const int s1 = (tid + 512) >> 6,  c41 = tid & 63;   // = s0+8, same col
    const size_t ustride = (size_t)BB * HH;

    if (tid < HH) hbuf[0][tid] = 0.0f;        // zeros are layout-invariant

    // prologue: stage chunk 0 -> buf 0 (compiler inserts the vmcnt wait)
    {
        const float4 v0 = *(const float4*)(u + ((size_t)s0 * BB + b) * HH + 4 * c40);
        const float4 v1 = *(const float4*)(u + ((size_t)s1 * BB + b) * HH + 4 * c41);
        *(float4*)&ubuf[0][s0][4 * c40] = v0;
        *(float4*)&ubuf[0][s1][4 * c41] = v1;
    }

    float* hp = hist + (size_t)b * HH + myrow;       // -> hist[t=0]
    float hreg = 0.f;                                // h[myrow] (both replicas)

    __syncthreads();

#define K2_BODY(T, S, MBUF, DO_STAGE, NBUF)                                  \
    {                                                                        \
        const int cur = (T) & 1;                                             \
        const float uval = ubuf[MBUF][S][myrow];                             \
        float4 h4[4];                                                        \
        _Pragma("unroll")                                                    \
        for (int j = 0; j < 4; ++j)                                          \
            h4[j] = *(const float4*)&hbuf[cur][64 * j + 4 * c];              \
        v2f acc[8];                                                          \
        _Pragma("unroll")                                                    \
        for (int r = 0; r < 8; ++r) acc[r] = (v2f)0.f;                       \
        _Pragma("unroll")                                                    \
        for (int j = 0; j < 4; ++j) {                                        \
            const v2f hA = (v2f){h4[j].x, h4[j].y};                          \
            const v2f hB = (v2f){h4[j].z, h4[j].w};                          \
            _Pragma("unroll")                                                \
            for (int r = 0; r < 8; ++r) {                                    \
                acc[r] += w2[r][2 * j] * hA;                                 \
                acc[r] += w2[r][2 * j + 1] * hB;                             \
            }                                                                \
        }                                                                    \
        float s_[8];                                                         \
        _Pragma("unroll")                                                    \
        for (int r = 0; r < 8; ++r) s_[r] = acc[r].x + acc[r].y;             \
        /* stage 1: xor8 (row_ror:8), halve by pb3: keep 4 rows */           \
        float t1[4];                                                         \
        _Pragma("unroll")                                                    \
        for (int i = 0; i < 4; ++i) {                                        \
            const float g = pb3 ? s_[i] : s_[i + 4];                         \
            const float k = pb3 ? s_[i + 4] : s_[i];                         \
            t1[i] = k + dpp_mov_f<0x128>(g);                                 \
        }                                                                    \
        /* stage 2: xor1 (quad_perm 1,0,3,2), halve by pb0: keep 2 */        \
        float t2[2];                                                         \
        _Pragma("unroll")                                                    \
        for (int i = 0; i < 2; ++i) {                                        \
            const float g = pb0 ? t1[i] : t1[i + 2];                         \
            const float k = pb0 ? t1[i + 2] : t1[i];                         \
            t2[i] = k + dpp_mov_f<0xB1>(g);                                  \
        }                                                                    \
        /* stage 3: xor2 (quad_perm 2,3,0,1), halve by pb1: keep 1 */        \
        float sr;                                                            \
        {                                                                    \
            const float g = pb1 ? t2[0] : t2[1];                             \
            const float k = pb1 ? t2[1] : t2[0];                             \
            sr = k + dpp_mov_f<0x4E>(g);                                     \
        }                                                                    \
        /* stage 4: xor4 via ds_swizzle (BitMode xor=4), full add */         \
        sr += __int_as_float(__builtin_amdgcn_ds_swizzle(                    \
                  __float_as_int(sr), 0x101F));                              \
        {                                                                    \
            const float sin_ = sr + uval;                                    \
            const float hnew = hreg + alpha * (ftanh(sin_) - hreg);          \
            if (own) {                                                       \
                *hp = hreg;                       /* pre-update h -> y[t] */ \
                hbuf[cur ^ 1][wpos] = hnew;                                  \
            }                                                                \
            hreg = hnew;                                                     \
        }                                                                    \
        hp += ustride;                                                       \
        if (DO_STAGE) {                                                      \
            /* write next u-chunk (loads issued at window start; vmcnt    */ \
            /* wait lands here, once per 16 steps)                        */ \
            *(float4*)&ubuf[NBUF][s0][4 * c40] = stv0;                       \
            *(float4*)&ubuf[NBUF][s1][4 * c41] = stv1;                       \
        }                                                                    \
        /* LDS-only drain + barrier: hist stores stay in flight */           \
        asm volatile("s_waitcnt lgkmcnt(0)\n\ts_barrier" ::: "memory");      \
    }

    for (int m = 0; m < NW; ++m) {
        const int mbuf = m & 1;
        const int nbuf = mbuf ^ 1;
        const bool more = (m + 1 < NW);
        // issue next-chunk global loads now; the asm "memory" barriers in the
        // bodies below keep them at this program point, giving ~15 steps of
        // latency slack before the DO_STAGE writes consume them.
        float4 stv0, stv1;
        if (more) {
            const size_t t0 = (size_t)(CHUNK * (m + 1));
            stv0 = *(const float4*)(u + ((t0 + s0) * BB + b) * HH + 4 * c40);
            stv1 = *(const float4*)(u + ((t0 + s1) * BB + b) * HH + 4 * c41);
        }
        #pragma unroll 4
        for (int s = 0; s < CHUNK; ++s) {
            const int t = CHUNK * m + s;
            const bool stage = (s == CHUNK - 1) && more;
            K2_BODY(t, s, mbuf, stage, nbuf)
        }
    }
#undef K2_BODY
}

// ---------------------------------------------------------------------------
// K3: y[e,o] = bout[o] + sum_k tanh(bhx[k] + sum_i hist[e,i]Whx[i,k]) * Wout[k,o]
// 32 rows/block, 256 threads. Same register-tiling scheme.
// ---------------------------------------------------------------------------
__global__ __launch_bounds__(256) void k3_y(
    const float* __restrict__ hist, const float* __restrict__ Whx,
    const float* __restrict__ bhx, const float* __restrict__ Wout,
    const float* __restrict__ bout, float* __restrict__ y)
{
    __shared__ float hs[32][HH];    // 32KB
    __shared__ float gs[32][DHH];   // 16KB
    const int tid = threadIdx.x;
    const size_t row0 = (size_t)blockIdx.x * 32;

    for (int v = tid; v < 32 * HH; v += 256) {
        int r = v >> 8, i = v & 255;
        hs[r][i] = hist[(row0 + r) * HH + i];
    }
    __syncthreads();

    // stage A: gs = tanh(hs @ Whx + bhx). cols aq+32j; rows 4ru..4ru+3. K=256
    {
        const int aq = tid & 31;
        const int ru = tid >> 5;
        v2f aA[4], aB[4];
        #pragma unroll
        for (int i = 0; i < 4; ++i) { aA[i] = (v2f)0.f; aB[i] = (v2f)0.f; }

        #pragma unroll
        for (int kc = 0; kc < 16; ++kc) {   // KC=16
            v2f wA[16], wB[16];
            #pragma unroll
            for (int k = 0; k < 16; ++k) {
                const float* wp = Whx + (size_t)(kc * 16 + k) * DHH + aq;
                wA[k] = (v2f){wp[0],  wp[32]};
                wB[k] = (v2f){wp[64], wp[96]};
            }
            #pragma unroll
            for (int k4 = 0; k4 < 4; ++k4) {
                float4 hv[4];
                #pragma unroll
                for (int i = 0; i < 4; ++i)
                    hv[i] = *(const float4*)&hs[4 * ru + i][kc * 16 + 4 * k4];
                #pragma unroll
                for (int i = 0; i < 4; ++i) {
                    #pragma unroll
                    for (int e = 0; e < 4; ++e) {
                        const float he = (e == 0) ? hv[i].x : (e == 1) ? hv[i].y
                                       : (e == 2) ? hv[i].z : hv[i].w;
                        const v2f hb = (v2f){he, he};
                        aA[i] += wA[4 * k4 + e] * hb;
                        aB[i] += wB[4 * k4 + e] * hb;
                    }
                }
            }
        }
        const float b0 = bhx[aq], b1 = bhx[aq + 32], b2 = bhx[aq + 64], b3 = bhx[aq + 96];
        #pragma unroll
        for (int i = 0; i < 4; ++i) {
            const int r = 4 * ru + i;
            gs[r][aq]      = ftanh(aA[i].x + b0);
            gs[r][aq + 32] = ftanh(aA[i].y + b1);
            gs[r][aq + 64] = ftanh(aB[i].x + b2);
            gs[r][aq + 96] = ftanh(aB[i].y + b3);
        }
    }
    __syncthreads();

    // stage B: y = gs @ Wout + bout. cols o2, o2+32; rows 4ru..4ru+3. K=128
    {
        const int o2 = tid & 31;
        const int ru = tid >> 5;
        v2f acc[4];
        #pragma unroll
        for (int i = 0; i < 4; ++i) acc[i] = (v2f)0.f;

        #pragma unroll
        for (int kc = 0; kc < 2; ++kc) {    // KC=64
            v2f w[64];
            #pragma unroll
            for (int k = 0; k < 64; ++k) {
                const float* wp = Wout + (size_t)(kc * 64 + k) * XDIM + o2;
                w[k] = (v2f){wp[0], wp[32]};
            }
            #pragma unroll
            for (int k4 = 0; k4 < 16; ++k4) {
                float4 gv[4];
                #pragma unroll
                for (int i = 0; i < 4; ++i)
                    gv[i] = *(const float4*)&gs[4 * ru + i][kc * 64 + 4 * k4];
                #pragma unroll
                for (int i = 0; i < 4; ++i) {
                    #pragma unroll
                    for (int e = 0; e < 4; ++e) {
                        const float ge = (e == 0) ? gv[i].x : (e == 1) ? gv[i].y
                                       : (e == 2) ? gv[i].z : gv[i].w;
                        acc[i] += w[4 * k4 + e] * (v2f){ge, ge};
                    }
                }
            }
        }
        const float b0 = bout[o2], b1 = bout[o2 + 32];
        #pragma unroll
        for (int i = 0; i < 4; ++i) {
            const size_t row = row0 + 4 * ru + i;
            y[row * XDIM + o2]      = acc[i].x + b0;
            y[row * XDIM + o2 + 32] = acc[i].y + b1;
        }
    }
}

extern "C" void kernel_launch(void* const* d_in, const int* in_sizes, int n_in,
                              void* d_out, int out_size, void* d_ws, size_t ws_size,
                              hipStream_t stream) {
    const float* x      = (const float*)d_in[0];
    const float* Wx     = (const float*)d_in[1];
    const float* bx     = (const float*)d_in[2];
    const float* Wih    = (const float*)d_in[3];
    const float* bih    = (const float*)d_in[4];
    const float* Whh    = (const float*)d_in[5];
    const float* bhh    = (const float*)d_in[6];
    const float* Whx    = (const float*)d_in[7];
    const float* bhx    = (const float*)d_in[8];
    const float* Wout   = (const float*)d_in[9];
    const float* bout   = (const float*)d_in[10];
    const float* sigmas = (const float*)d_in[11];
    float* y = (float*)d_out;

    float* u    = (float*)d_ws;                   // S*B*H floats = 128 MB
    float* hist = u + (size_t)SS * BB * HH;       // S*B*H floats = 128 MB

    k1_featu<<<(SS * BB) / 64, 256, 0, stream>>>(x, Wx, bx, Wih, bih, bhh, u);
    k2_rnn<<<BB, 512, 0, stream>>>(u, Whh, sigmas, hist);
    k3_y<<<(SS * BB) / 32, 256, 0, stream>>>(hist, Whx, bhx, Wout, bout, y);
}

// Round 20
// 1726.841 us; speedup vs baseline: 11.7221x; 1.0448x over previous
//
#include <hip/hip_runtime.h>
#include <math.h>

#define SS 2048
#define BB 64
#define XDIM 64
#define DXF 128
#define HH 256
#define DHH 128
#define CHUNK 16
#define NW (SS / CHUNK)   // 128 windows

typedef float v2f __attribute__((ext_vector_type(2)));

// tanh(x) = 1 - 2/(exp(2x)+1); __expf -> v_exp_f32, ~1e-6 abs err, saturates correctly.
__device__ __forceinline__ float ftanh(float x) {
    float e = __expf(2.0f * x);
    return 1.0f - 2.0f / (e + 1.0f);
}

template <int CTRL>
__device__ __forceinline__ float dpp_mov_f(float x) {
    return __int_as_float(__builtin_amdgcn_update_dpp(
        0, __float_as_int(x), CTRL, 0xF, 0xF, true));
}

// ---------------------------------------------------------------------------
// K1: u[e,i] = bih[i]+bhh[i] + sum_j tanh(bx[j] + sum_m x[e,m]Wx[m,j]) * Wih[i,j]
// 64 rows/block, 256 threads. Register tiles: 4 cols x 4 rows, float4 LDS reads.
// ---------------------------------------------------------------------------
__global__ __launch_bounds__(256) void k1_featu(
    const float* __restrict__ x, const float* __restrict__ Wx,
    const float* __restrict__ bx, const float* __restrict__ Wih,
    const float* __restrict__ bih, const float* __restrict__ bhh,
    float* __restrict__ u)
{
    __shared__ float xs[64][XDIM];   // 16KB
    __shared__ float fs[64][DXF];    // 32KB
    const int tid = threadIdx.x;
    const size_t row0 = (size_t)blockIdx.x * 64;

    for (int v = tid; v < 64 * XDIM; v += 256) {
        int r = v >> 6, m = v & 63;
        xs[r][m] = x[(row0 + r) * XDIM + m];
    }
    __syncthreads();

    // stage 2: fs = tanh(xs @ Wx + bx). cols: cq+32j; rows: 8ru..8ru+7
    {
        const int cq = tid & 31;
        const int ru = tid >> 5;
        v2f aA[2][4], aB[2][4];
        #pragma unroll
        for (int g = 0; g < 2; ++g)
            #pragma unroll
            for (int i = 0; i < 4; ++i) { aA[g][i] = (v2f)0.f; aB[g][i] = (v2f)0.f; }

        #pragma unroll
        for (int kc = 0; kc < 4; ++kc) {          // K=64, KC=16
            v2f wA[16], wB[16];
            #pragma unroll
            for (int k = 0; k < 16; ++k) {
                const float* wp = Wx + (kc * 16 + k) * DXF + cq;
                wA[k] = (v2f){wp[0],  wp[32]};
                wB[k] = (v2f){wp[64], wp[96]};
            }
            #pragma unroll
            for (int g = 0; g < 2; ++g) {
                const int rb = 8 * ru + 4 * g;
                #pragma unroll
                for (int k4 = 0; k4 < 4; ++k4) {
                    float4 xv[4];
                    #pragma unroll
                    for (int i = 0; i < 4; ++i)
                        xv[i] = *(const float4*)&xs[rb + i][kc * 16 + 4 * k4];
                    #pragma unroll
                    for (int i = 0; i < 4; ++i) {
                        #pragma unroll
                        for (int e = 0; e < 4; ++e) {
                            const float xe = (e == 0) ? xv[i].x : (e == 1) ? xv[i].y
                                           : (e == 2) ? xv[i].z : xv[i].w;
                            const v2f xb = (v2f){xe, xe};
                            aA[g][i] += wA[4 * k4 + e] * xb;
                            aB[g][i] += wB[4 * k4 + e] * xb;
                        }
                    }
                }
            }
        }
        const float b0 = bx[cq], b1 = bx[cq + 32], b2 = bx[cq + 64], b3 = bx[cq + 96];
        #pragma unroll
        for (int g = 0; g < 2; ++g)
            #pragma unroll
            for (int i = 0; i < 4; ++i) {
                const int r = 8 * ru + 4 * g + i;
                fs[r][cq]      = ftanh(aA[g][i].x + b0);
                fs[r][cq + 32] = ftanh(aA[g][i].y + b1);
                fs[r][cq + 64] = ftanh(aB[g][i].x + b2);
                fs[r][cq + 96] = ftanh(aB[g][i].y + b3);
            }
    }
    __syncthreads();

    // stage 3: u = fs @ Wih^T + bih + bhh. cols q4+64j; rows 16rq..16rq+15
    {
        const int q4 = tid & 63;
        const int rq = tid >> 6;
        v2f aA[4][4], aB[4][4];
        #pragma unroll
        for (int g = 0; g < 4; ++g)
            #pragma unroll
            for (int i = 0; i < 4; ++i) { aA[g][i] = (v2f)0.f; aB[g][i] = (v2f)0.f; }

        #pragma unroll
        for (int kc = 0; kc < 8; ++kc) {          // K=128, KC=16
            v2f wA[16], wB[16];
            #pragma unroll
            for (int k4 = 0; k4 < 4; ++k4) {
                const float4 w0 = *(const float4*)(Wih + (size_t)(q4      ) * DXF + kc * 16 + 4 * k4);
                const float4 w1 = *(const float4*)(Wih + (size_t)(q4 +  64) * DXF + kc * 16 + 4 * k4);
                const float4 w2 = *(const float4*)(Wih + (size_t)(q4 + 128) * DXF + kc * 16 + 4 * k4);
                const float4 w3 = *(const float4*)(Wih + (size_t)(q4 + 192) * DXF + kc * 16 + 4 * k4);
                wA[4 * k4 + 0] = (v2f){w0.x, w1.x}; wA[4 * k4 + 1] = (v2f){w0.y, w1.y};
                wA[4 * k4 + 2] = (v2f){w0.z, w1.z}; wA[4 * k4 + 3] = (v2f){w0.w, w1.w};
                wB[4 * k4 + 0] = (v2f){w2.x, w3.x}; wB[4 * k4 + 1] = (v2f){w2.y, w3.y};
                wB[4 * k4 + 2] = (v2f){w2.z, w3.z}; wB[4 * k4 + 3] = (v2f){w2.w, w3.w};
            }
            #pragma unroll
            for (int g = 0; g < 4; ++g) {
                const int rb = 16 * rq + 4 * g;
                #pragma unroll
                for (int k4 = 0; k4 < 4; ++k4) {
                    float4 fv[4];
                    #pragma unroll
                    for (int i = 0; i < 4; ++i)
                        fv[i] = *(const float4*)&fs[rb + i][kc * 16 + 4 * k4];
                    #pragma unroll
                    for (int i = 0; i < 4; ++i) {
                        #pragma unroll
                        for (int e = 0; e < 4; ++e) {
                            const float fe = (e == 0) ? fv[i].x : (e == 1) ? fv[i].y
                                           : (e == 2) ? fv[i].z : fv[i].w;
                            const v2f fb = (v2f){fe, fe};
                            aA[g][i] += wA[4 * k4 + e] * fb;
                            aB[g][i] += wB[4 * k4 + e] * fb;
                        }
                    }
                }
            }
        }
        const float b0 = bih[q4]       + bhh[q4];
        const float b1 = bih[q4 + 64]  + bhh[q4 + 64];
        const float b2 = bih[q4 + 128] + bhh[q4 + 128];
        const float b3 = bih[q4 + 192] + bhh[q4 + 192];
        #pragma unroll
        for (int g = 0; g < 4; ++g)
            #pragma unroll
            for (int i = 0; i < 4; ++i) {
                const size_t row = row0 + 16 * rq + 4 * g + i;
                u[row * HH + q4]       = aA[g][i].x + b0;
                u[row * HH + q4 + 64]  = aA[g][i].y + b1;
                u[row * HH + q4 + 128] = aB[g][i].x + b2;
                u[row * HH + q4 + 192] = aB[g][i].y + b3;
            }
    }
}

// ---------------------------------------------------------------------------
// K2: sequential recurrence. R25 = R24 resubmit (infra failure, never ran).
// R24 = R22 passing base (512 thr, 8 waves, 1 batch/block, 1311us) + two
// chain cuts, with the R23 bug fixed.
//
// R23 post-mortem (FAILED, absmax 0.84): row_ror:4 direction. row_ror:N
// delivers src lane (i-N) mod 16; N=8 is direction-symmetric (why 0x128
// always passed) but N=4 sent owner lane 0 lane 12's partial, not lane 4's.
// FIX: stage-4 xor4 exchange built from three LANE-EXACT permutations
// (each verified in passing kernels): i^7 (row_half_mirror 0x141) ->
// i^2 (quad_perm 0x4E) -> i^1 (quad_perm 0xB1); XOR masks compose:
// 7^2^1 = 4. ~24cy on the chain vs ds_swizzle's ~120cy LDS round-trip.
// Chain cut #2: uval prefetched one step ahead (hidden under the FMA
// block); window-head value seeded right after the barrier that published
// the staged buffer.
// Everything else byte-identical to R22: chunked-u double-buffered staging,
// de-interleaved h layout (4x b128/lane, 2-way-bank class), value-halving
// reduce xor8(0x128,pb3)/xor1(0xB1,pb0)/xor2(0x4E,pb1), rl=4*pb3+2*pb0+pb1,
// owner c&4==0, lgkm-only barrier.
// ---------------------------------------------------------------------------
__global__ __launch_bounds__(512)
void k2_rnn(
    const float* __restrict__ u, const float* __restrict__ Whh,
    const float* __restrict__ sigmas, float* __restrict__ hist)
{
    __shared__ float hbuf[2][HH];          // de-interleaved, 2KB
    __shared__ float ubuf[2][CHUNK][HH];   // [buf][step][row] 32KB
    const int tid = threadIdx.x;
    const int b = blockIdx.x;
    const int c  = tid & 15;               // k-chunk: ks [16c, 16c+16)
    const int rg = tid >> 4;               // row group: rows [8rg, 8rg+8)

    // weights: w2[r][2j]   = {Whh[8rg+r][16c+4j],   [16c+4j+1]}
    //          w2[r][2j+1] = {Whh[8rg+r][16c+4j+2], [16c+4j+3]}
    v2f w2[8][8];
    #pragma unroll
    for (int r = 0; r < 8; ++r) {
        const float* wrow = Whh + (size_t)(8 * rg + r) * HH + 16 * c;
        #pragma unroll
        for (int j = 0; j < 4; ++j) {
            const float4 wv = *(const float4*)(wrow + 4 * j);
            w2[r][2 * j]     = (v2f){wv.x, wv.y};
            w2[r][2 * j + 1] = (v2f){wv.z, wv.w};
        }
    }
    // Pin: asm results are non-rematerializable -> stay resident all loop.
    #pragma unroll
    for (int r = 0; r < 8; r += 2) {
        asm volatile("" : "+v"(w2[r][0]),     "+v"(w2[r][1]),     "+v"(w2[r][2]),     "+v"(w2[r][3]),
                          "+v"(w2[r][4]),     "+v"(w2[r][5]),     "+v"(w2[r][6]),     "+v"(w2[r][7]),
                          "+v"(w2[r + 1][0]), "+v"(w2[r + 1][1]), "+v"(w2[r + 1][2]), "+v"(w2[r + 1][3]),
                          "+v"(w2[r + 1][4]), "+v"(w2[r + 1][5]), "+v"(w2[r + 1][6]), "+v"(w2[r + 1][7]));
    }

    const int pb0 = c & 1;
    const int pb1 = (c >> 1) & 1;
    const int pb3 = (c >> 3) & 1;
    const int rl = 4 * pb3 + 2 * pb0 + pb1;   // local row after halvings
    const int myrow = 8 * rg + rl;            // 2 replica lanes (c, c^4)
    const bool own = ((c & 4) == 0);          // one store-owner per row

    const float alpha = 1.f / (1.f + __expf(-sigmas[myrow & 3]));

    // de-interleaved position of myrow for the hbuf store
    const int wpos = 64 * ((myrow >> 2) & 3) + 4 * (myrow >> 4) + (myrow & 3);

    // u staging geometry: float4-index space [0,1024) covered twice:
    // p = tid + 512k -> step s = p>>6, float4 col c4 = p&63
    const int s0 = tid >> 6,          c40 = tid & 63;
    const int s1 = (tid + 512) >> 6,  c41 = tid & 63;   // = s0+8, same col
    const size_t ustride = (size_t)BB * HH;

    if (tid < HH) hbuf[0][tid] = 0.0f;        // zeros are layout-invariant

    // prologue: stage chunk 0 -> buf 0 (compiler inserts the vmcnt wait)
    {
        const float4 v0 = *(const float4*)(u + ((size_t)s0 * BB + b) * HH + 4 * c40);
        const float4 v1 = *(const float4*)(u + ((size_t)s1 * BB + b) * HH + 4 * c41);
        *(float4*)&ubuf[0][s0][4 * c40] = v0;
        *(float4*)&ubuf[0][s1][4 * c41] = v1;
    }

    float* hp = hist + (size_t)b * HH + myrow;       // -> hist[t=0]
    float hreg = 0.f;                                // h[myrow]

    __syncthreads();

#define K2_BODY(T, S, MBUF, DO_STAGE, NBUF)                                  \
    {                                                                        \
        const int cur = (T) & 1;                                             \
        float4 h4[4];                                                        \
        _Pragma("unroll")                                                    \
        for (int j = 0; j < 4; ++j)                                          \
            h4[j] = *(const float4*)&hbuf[cur][64 * j + 4 * c];              \
        /* prefetch next step's u (hidden under the FMA block) */            \
        float unext = 0.f;                                                   \
        if ((S) < CHUNK - 1) unext = ubuf[MBUF][(S) + 1][myrow];             \
        v2f acc[8];                                                          \
        _Pragma("unroll")                                                    \
        for (int r = 0; r < 8; ++r) acc[r] = (v2f)0.f;                       \
        _Pragma("unroll")                                                    \
        for (int j = 0; j < 4; ++j) {                                        \
            const v2f hA = (v2f){h4[j].x, h4[j].y};                          \
            const v2f hB = (v2f){h4[j].z, h4[j].w};                          \
            _Pragma("unroll")                                                \
            for (int r = 0; r < 8; ++r) {                                    \
                acc[r] += w2[r][2 * j] * hA;                                 \
                acc[r] += w2[r][2 * j + 1] * hB;                             \
            }                                                                \
        }                                                                    \
        float s_[8];                                                         \
        _Pragma("unroll")                                                    \
        for (int r = 0; r < 8; ++r) s_[r] = acc[r].x + acc[r].y;             \
        /* stage 1: xor8 (row_ror:8, direction-symmetric), halve by pb3 */   \
        float t1[4];                                                         \
        _Pragma("unroll")                                                    \
        for (int i = 0; i < 4; ++i) {                                        \
            const float g = pb3 ? s_[i] : s_[i + 4];                         \
            const float k = pb3 ? s_[i + 4] : s_[i];                         \
            t1[i] = k + dpp_mov_f<0x128>(g);                                 \
        }                                                                    \
        /* stage 2: xor1 (quad_perm 1,0,3,2), halve by pb0: keep 2 */        \
        float t2[2];                                                         \
        _Pragma("unroll")                                                    \
        for (int i = 0; i < 2; ++i) {                                        \
            const float g = pb0 ? t1[i] : t1[i + 2];                         \
            const float k = pb0 ? t1[i + 2] : t1[i];                         \
            t2[i] = k + dpp_mov_f<0xB1>(g);                                  \
        }                                                                    \
        /* stage 3: xor2 (quad_perm 2,3,0,1), halve by pb1: keep 1 */        \
        float sr;                                                            \
        {                                                                    \
            const float g = pb1 ? t2[0] : t2[1];                             \
            const float k = pb1 ? t2[1] : t2[0];                             \
            sr = k + dpp_mov_f<0x4E>(g);                                     \
        }                                                                    \
        /* stage 4: xor4 full add via composite of EXACT permutations:   */ \
        /* i^7 (half_mirror) -> i^2 (quad_perm) -> i^1 (quad_perm) = i^4 */ \
        {                                                                    \
            float m1 = dpp_mov_f<0x141>(sr);                                 \
            m1 = dpp_mov_f<0x4E>(m1);                                        \
            m1 = dpp_mov_f<0xB1>(m1);                                        \
            sr += m1;                                                        \
        }                                                                    \
        {                                                                    \
            const float sin_ = sr + uq;                                      \
            const float hnew = hreg + alpha * (ftanh(sin_) - hreg);          \
            if (own) {                                                       \
                *hp = hreg;                       /* pre-update h -> y[t] */ \
                hbuf[cur ^ 1][wpos] = hnew;                                  \
            }                                                                \
            hreg = hnew;                                                     \
        }                                                                    \
        uq = unext;                                                          \
        hp += ustride;                                                       \
        if (DO_STAGE) {                                                      \
            /* write next u-chunk (loads issued at window start; vmcnt    */ \
            /* wait lands here, once per 16 steps)                        */ \
            *(float4*)&ubuf[NBUF][s0][4 * c40] = stv0;                       \
            *(float4*)&ubuf[NBUF][s1][4 * c41] = stv1;                       \
        }                                                                    \
        /* LDS-only drain + barrier: hist stores stay in flight */           \
        asm volatile("s_waitcnt lgkmcnt(0)\n\ts_barrier" ::: "memory");      \
    }

    // uq = u value for the CURRENT step; seeded at each window head (safe:
    // the staged buffer was published by the barrier that ended the
    // previous window).
    float uq = ubuf[0][0][myrow];

    for (int m = 0; m < NW; ++m) {
        const int mbuf = m & 1;
        const int nbuf = mbuf ^ 1;
        const bool more = (m + 1 < NW);
        if (m > 0) uq = ubuf[mbuf][0][myrow];   // window-head seed
        // issue next-chunk global loads now; the asm "memory" barriers in the
        // bodies below keep them at this program point, giving ~15 steps of
        // latency slack before the DO_STAGE writes consume them.
        float4 stv0, stv1;
        if (more) {
            const size_t t0 = (size_t)(CHUNK * (m + 1));
            stv0 = *(const float4*)(u + ((t0 + s0) * BB + b) * HH + 4 * c40);
            stv1 = *(const float4*)(u + ((t0 + s1) * BB + b) * HH + 4 * c41);
        }
        #pragma unroll 4
        for (int s = 0; s < CHUNK; ++s) {
            const int t = CHUNK * m + s;
            const bool stage = (s == CHUNK - 1) && more;
            K2_BODY(t, s, mbuf, stage, nbuf)
        }
    }
#undef K2_BODY
}

// ---------------------------------------------------------------------------
// K3: y[e,o] = bout[o] + sum_k tanh(bhx[k] + sum_i hist[e,i]Whx[i,k]) * Wout[k,o]
// 32 rows/block, 256 threads. Same register-tiling scheme.
// ---------------------------------------------------------------------------
__global__ __launch_bounds__(256) void k3_y(
    const float* __restrict__ hist, const float* __restrict__ Whx,
    const float* __restrict__ bhx, const float* __restrict__ Wout,
    const float* __restrict__ bout, float* __restrict__ y)
{
    __shared__ float hs[32][HH];    // 32KB
    __shared__ float gs[32][DHH];   // 16KB
    const int tid = threadIdx.x;
    const size_t row0 = (size_t)blockIdx.x * 32;

    for (int v = tid; v < 32 * HH; v += 256) {
        int r = v >> 8, i = v & 255;
        hs[r][i] = hist[(row0 + r) * HH + i];
    }
    __syncthreads();

    // stage A: gs = tanh(hs @ Whx + bhx). cols aq+32j; rows 4ru..4ru+3. K=256
    {
        const int aq = tid & 31;
        const int ru = tid >> 5;
        v2f aA[4], aB[4];
        #pragma unroll
        for (int i = 0; i < 4; ++i) { aA[i] = (v2f)0.f; aB[i] = (v2f)0.f; }

        #pragma unroll
        for (int kc = 0; kc < 16; ++kc) {   // KC=16
            v2f wA[16], wB[16];
            #pragma unroll
            for (int k = 0; k < 16; ++k) {
                const float* wp = Whx + (size_t)(kc * 16 + k) * DHH + aq;
                wA[k] = (v2f){wp[0],  wp[32]};
                wB[k] = (v2f){wp[64], wp[96]};
            }
            #pragma unroll
            for (int k4 = 0; k4 < 4; ++k4) {
                float4 hv[4];
                #pragma unroll
                for (int i = 0; i < 4; ++i)
                    hv[i] = *(const float4*)&hs[4 * ru + i][kc * 16 + 4 * k4];
                #pragma unroll
                for (int i = 0; i < 4; ++i) {
                    #pragma unroll
                    for (int e = 0; e < 4; ++e) {
                        const float he = (e == 0) ? hv[i].x : (e == 1) ? hv[i].y
                                       : (e == 2) ? hv[i].z : hv[i].w;
                        const v2f hb = (v2f){he, he};
                        aA[i] += wA[4 * k4 + e] * hb;
                        aB[i] += wB[4 * k4 + e] * hb;
                    }
                }
            }
        }
        const float b0 = bhx[aq], b1 = bhx[aq + 32], b2 = bhx[aq + 64], b3 = bhx[aq + 96];
        #pragma unroll
        for (int i = 0; i < 4; ++i) {
            const int r = 4 * ru + i;
            gs[r][aq]      = ftanh(aA[i].x + b0);
            gs[r][aq + 32] = ftanh(aA[i].y + b1);
            gs[r][aq + 64] = ftanh(aB[i].x + b2);
            gs[r][aq + 96] = ftanh(aB[i].y + b3);
        }
    }
    __syncthreads();

    // stage B: y = gs @ Wout + bout. cols o2, o2+32; rows 4ru..4ru+3. K=128
    {
        const int o2 = tid & 31;
        const int ru = tid >> 5;
        v2f acc[4];
        #pragma unroll
        for (int i = 0; i < 4; ++i) acc[i] = (v2f)0.f;

        #pragma unroll
        for (int kc = 0; kc < 2; ++kc) {    // KC=64
            v2f w[64];
            #pragma unroll
            for (int k = 0; k < 64; ++k) {
                const float* wp = Wout + (size_t)(kc * 64 + k) * XDIM + o2;
                w[k] = (v2f){wp[0], wp[32]};
            }
            #pragma unroll
            for (int k4 = 0; k4 < 16; ++k4) {
                float4 gv[4];
                #pragma unroll
                for (int i = 0; i < 4; ++i)
                    gv[i] = *(const float4*)&gs[4 * ru + i][kc * 64 + 4 * k4];
                #pragma unroll
                for (int i = 0; i < 4; ++i) {
                    #pragma unroll
                    for (int e = 0; e < 4; ++e) {
                        const float ge = (e == 0) ? gv[i].x : (e == 1) ? gv[i].y
                                       : (e == 2) ? gv[i].z : gv[i].w;
                        acc[i] += w[4 * k4 + e] * (v2f){ge, ge};
                    }
                }
            }
        }
        const float b0 = bout[o2], b1 = bout[o2 + 32];
        #pragma unroll
        for (int i = 0; i < 4; ++i) {
            const size_t row = row0 + 4 * ru + i;
            y[row * XDIM + o2]      = acc[i].x + b0;
            y[row * XDIM + o2 + 32] = acc[i].y + b1;
        }
    }
}

extern "C" void kernel_launch(void* const* d_in, const int* in_sizes, int n_in,
                              void* d_out, int out_size, void* d_ws, size_t ws_size,
                              hipStream_t stream) {
    const float* x      = (const float*)d_in[0];
    const float* Wx     = (const float*)d_in[1];
    const float* bx     = (const float*)d_in[2];
    const float* Wih    = (const float*)d_in[3];
    const float* bih    = (const float*)d_in[4];
    const float* Whh    = (const float*)d_in[5];
    const float* bhh    = (const float*)d_in[6];
    const float* Whx    = (const float*)d_in[7];
    const float* bhx    = (const float*)d_in[8];
    const float* Wout   = (const float*)d_in[9];
    const float* bout   = (const float*)d_in[10];
    const float* sigmas = (const float*)d_in[11];
    float* y = (float*)d_out;

    float* u    = (float*)d_ws;                   // S*B*H floats = 128 MB
    float* hist = u + (size_t)SS * BB * HH;       // S*B*H floats = 128 MB

    k1_featu<<<(SS * BB) / 64, 256, 0, stream>>>(x, Wx, bx, Wih, bih, bhh, u);
    k2_rnn<<<BB, 512, 0, stream>>>(u, Whh, sigmas, hist);
    k3_y<<<(SS * BB) / 32, 256, 0, stream>>>(hist, Whx, bhx, Wout, bout, y);
}